// Round 14
// baseline (1544.791 us; speedup 1.0000x reference)
//
#include <hip/hip_runtime.h>
#include <hip/hip_cooperative_groups.h>
#include <cstdint>
#include <cstddef>

namespace cg = cooperative_groups;

// ---------------------------------------------------------------------------
// GraphSAGE 3-layer forward.
//   layer: out = act( mean_gather(h @ W_l) + (h @ W_r + b) )   (linearity swap)
// R13 (336us, banked): 12 dispatches; ~110us of inter-dispatch gaps.
// R14: cooperative mega-kernel, grid sized from hipOccupancyMaxActiveBlocks
//   (R12 failed: hard-coded 1024 blocks > co-resident capacity -- unified
//   VGPR/AGPR file pushed blocks/CU below 4). Fallback to the proven
//   12-dispatch path if the cooperative launch errors (worst case = R13).
//   All phases are gridDim.x-strided device functions shared by both paths.
// NOTE: harness delivers integer inputs as int32 -> edge_index is const int*.
// ---------------------------------------------------------------------------

#define HID 128
#define NSLICE 8

using short8 = __attribute__((ext_vector_type(8))) short;
using f32x4  = __attribute__((ext_vector_type(4))) float;

// ---- bf16 helpers (manual, RNE) -------------------------------------------

__device__ __forceinline__ unsigned short f32_to_bf16(float f)
{
    union { float f; unsigned int i; } c; c.f = f;
    const unsigned int x = c.i;
    const unsigned int r = x + 0x7fffu + ((x >> 16) & 1u);
    return (unsigned short)(r >> 16);
}

__device__ __forceinline__ float bf16_hi_to_f32(unsigned int hi16_in_low)
{
    union { unsigned int i; float f; } c; c.i = hi16_in_low << 16;
    return c.f;
}

// ---- params ---------------------------------------------------------------

struct MegaParams {
    const float* x;
    const int*   src;
    const int*   dst;
    const float *wl0, *b0, *wr0, *wl1, *b1, *wr1, *wl2, *b2, *wr2;
    float*       out;
    int N, E;
    int *offs, *cursor, *deg, *partials, *esrc;
    unsigned short *pbuf, *rb16, *hbf, *wt0, *wt1, *wt2;
    float* rbf32;
};

// ---- phase: zero deg + W^T prep (independent, fused) ----------------------

__device__ __forceinline__ void dev_init(const MegaParams& P)
{
    const int tid = blockIdx.x * 256 + threadIdx.x;
    const int nth = gridDim.x * 256;
    for (int i = tid; i < P.N; i += nth) P.deg[i] = 0;
    const int per128 = 2 * HID * HID;              // 32768
    const int total  = 2 * per128 + 2 * 64 * HID;  // 81920
    for (int i = tid; i < total; i += nth) {
        if (i < per128) {
            const int k = i & (HID - 1), c = i >> 7;
            const float v = (c < HID) ? P.wl0[(size_t)k * HID + c]
                                      : P.wr0[(size_t)k * HID + (c - HID)];
            P.wt0[i] = f32_to_bf16(v);
        } else if (i < 2 * per128) {
            const int j = i - per128;
            const int k = j & (HID - 1), c = j >> 7;
            const float v = (c < HID) ? P.wl1[(size_t)k * HID + c]
                                      : P.wr1[(size_t)k * HID + (c - HID)];
            P.wt1[j] = f32_to_bf16(v);
        } else {
            const int j = i - 2 * per128;
            const int k = j & (HID - 1), c = j >> 7;
            const float v = (c < 64) ? P.wl2[(size_t)k * 64 + c]
                                     : P.wr2[(size_t)k * 64 + (c - 64)];
            P.wt2[j] = f32_to_bf16(v);
        }
    }
}

// ---- phase: degree histogram ----------------------------------------------

__device__ __forceinline__ void dev_hist(const MegaParams& P)
{
    const int tid = blockIdx.x * 256 + threadIdx.x;
    const int nth = gridDim.x * 256;
    for (int e = tid; e < P.E; e += nth) {
        const int d = P.dst[e];
        if (d >= 0 && d < P.N) atomicAdd(&P.deg[d], 1);
    }
}

// ---- phase: per-chunk sums (chunk = 1024 deg entries) ---------------------

__device__ __forceinline__ void dev_blocksum(const MegaParams& P)
{
    __shared__ int red[256];
    const int nChunk = (P.N + 1023) >> 10;
    const int t = threadIdx.x;
    for (int c = blockIdx.x; c < nChunk; c += gridDim.x) {
        const int base = c << 10;
        int s = 0;
#pragma unroll
        for (int j = 0; j < 4; ++j) {
            const int idx = base + t * 4 + j;
            s += (idx < P.N) ? P.deg[idx] : 0;
        }
        red[t] = s;
        __syncthreads();
        for (int off = 128; off > 0; off >>= 1) {
            if (t < off) red[t] += red[t + off];
            __syncthreads();
        }
        if (t == 0) P.partials[c] = red[0];
        __syncthreads();
    }
}

// ---- phase: scan + write offs/cursor (fused prefix-of-partials) -----------

__device__ __forceinline__ void dev_scanwrite(const MegaParams& P)
{
    __shared__ int red[256];
    __shared__ int buf[256];
    const int nChunk = (P.N + 1023) >> 10;
    const int t = threadIdx.x;
    for (int c = blockIdx.x; c < nChunk; c += gridDim.x) {
        const int base = c << 10;
        red[t] = (t < c) ? P.partials[t] : 0;
        __syncthreads();
        for (int off = 128; off > 0; off >>= 1) {
            if (t < off) red[t] += red[t + off];
            __syncthreads();
        }
        const int blockBase = red[0];
        __syncthreads();

        int loc[4];
        int s = 0;
#pragma unroll
        for (int j = 0; j < 4; ++j) {
            const int idx = base + t * 4 + j;
            const int d = (idx < P.N) ? P.deg[idx] : 0;
            loc[j] = s;
            s += d;
        }
        buf[t] = s;
        __syncthreads();
        for (int off = 1; off < 256; off <<= 1) {
            const int u = (t >= off) ? buf[t - off] : 0;
            __syncthreads();
            buf[t] += u;
            __syncthreads();
        }
        const int tbase = blockBase + ((t == 0) ? 0 : buf[t - 1]);
#pragma unroll
        for (int j = 0; j < 4; ++j) {
            const int idx = base + t * 4 + j;
            if (idx < P.N) {
                const int o = tbase + loc[j];
                P.offs[idx] = o;
                P.cursor[idx] = o;
            }
        }
        __syncthreads();
    }
    if (blockIdx.x == 0 && t == 0) P.offs[P.N] = P.E;
}

// ---- phase: dst-sliced CSR fill (slice = blockIdx&7 for L2 locality) ------

__device__ __forceinline__ void dev_fill(const MegaParams& P)
{
    const int slice = blockIdx.x & (NSLICE - 1);
    const int nps   = (P.N + NSLICE - 1) / NSLICE;
    const int lo    = slice * nps;
    const int hi    = min(lo + nps, P.N);
    const int stride = (gridDim.x >> 3) * 256;
    for (int e = (blockIdx.x >> 3) * 256 + threadIdx.x; e < P.E; e += stride) {
        const int d = P.dst[e];
        if (d >= lo && d < hi) {
            const int s = P.src[e];
            if ((unsigned)s < (unsigned)P.N) {
                const int pos = atomicAdd(&P.cursor[d], 1);
                P.esrc[pos] = s;
            }
        }
    }
}

// ---- phase: MFMA dual GEMM  p = bf16(h@Wl), r = h@Wr + b ------------------
// 4 waves/block; wave owns 64 cols; B-frags resident; gridDim-stride slabs.

template <int DOUT, bool IN_F32, bool R_BF16>
__device__ __forceinline__ void dev_gemm(
    const void* __restrict__ hin, const unsigned short* __restrict__ wtc,
    const float* __restrict__ bias,
    unsigned short* __restrict__ p, void* __restrict__ r, int n)
{
    constexpr int TOTC = 2 * DOUT;
    constexpr int CPW  = TOTC / 64;   // 4 (DOUT=128) or 2 (DOUT=64)

    const int tx   = threadIdx.x;
    const int wv   = tx >> 6;
    const int lane = tx & 63;
    const int quad = lane >> 4;
    const int l15  = lane & 15;

    short8 B[CPW][4];
#pragma unroll
    for (int t = 0; t < CPW; ++t) {
        const int c = (wv * CPW + t) * 16 + l15;
#pragma unroll
        for (int q = 0; q < 4; ++q)
            B[t][q] = *(const short8*)(wtc + (size_t)c * HID + q * 32 + quad * 8);
    }

    const int slabs = (n + 15) >> 4;
    for (int slab = blockIdx.x; slab < slabs; slab += gridDim.x) {
        const int r0 = slab * 16;
        const int rr = min(r0 + l15, n - 1);

        short8 A[4];
        if (IN_F32) {
            const float* hf = (const float*)hin;
#pragma unroll
            for (int q = 0; q < 4; ++q) {
                const float4 f0 = *(const float4*)(hf + (size_t)rr * HID + q * 32 + quad * 8);
                const float4 f1 = *(const float4*)(hf + (size_t)rr * HID + q * 32 + quad * 8 + 4);
                short8 a;
                a[0] = (short)f32_to_bf16(f0.x); a[1] = (short)f32_to_bf16(f0.y);
                a[2] = (short)f32_to_bf16(f0.z); a[3] = (short)f32_to_bf16(f0.w);
                a[4] = (short)f32_to_bf16(f1.x); a[5] = (short)f32_to_bf16(f1.y);
                a[6] = (short)f32_to_bf16(f1.z); a[7] = (short)f32_to_bf16(f1.w);
                A[q] = a;
            }
        } else {
            const unsigned short* hb = (const unsigned short*)hin;
#pragma unroll
            for (int q = 0; q < 4; ++q)
                A[q] = *(const short8*)(hb + (size_t)rr * HID + q * 32 + quad * 8);
        }

        f32x4 acc[CPW];
#pragma unroll
        for (int t = 0; t < CPW; ++t) acc[t] = (f32x4){0.f, 0.f, 0.f, 0.f};
#pragma unroll
        for (int q = 0; q < 4; ++q)
#pragma unroll
            for (int t = 0; t < CPW; ++t)
                acc[t] = __builtin_amdgcn_mfma_f32_16x16x32_bf16(A[q], B[t][q], acc[t], 0, 0, 0);

        // epilogue: C/D layout col=l15, row=quad*4+i
#pragma unroll
        for (int t = 0; t < CPW; ++t) {
            const int c0  = (wv * CPW + t) * 16;
            const int col = c0 + l15;
            if (c0 < DOUT) {
#pragma unroll
                for (int i = 0; i < 4; ++i) {
                    const int row = r0 + quad * 4 + i;
                    if (row < n) p[(size_t)row * DOUT + col] = f32_to_bf16(acc[t][i]);
                }
            } else {
                const float bv = bias[col - DOUT];
#pragma unroll
                for (int i = 0; i < 4; ++i) {
                    const int row = r0 + quad * 4 + i;
                    if (row < n) {
                        const float v = acc[t][i] + bv;
                        if (R_BF16)
                            ((unsigned short*)r)[(size_t)row * DOUT + (col - DOUT)] = f32_to_bf16(v);
                        else
                            ((float*)r)[(size_t)row * DOUT + (col - DOUT)] = v;
                    }
                }
            }
        }
    }
}

// ---- phase: post-aggregation  out = act(mean(p[nbrs]) + r) ----------------
// One wave per node, gridDim-stride; predicated x8 unroll.

template <int DOUT, bool RELU, bool OUTBF16, bool R_BF16>
__device__ __forceinline__ void dev_agg(
    const unsigned short* __restrict__ p, const void* __restrict__ r,
    const int* __restrict__ offs, const int* __restrict__ esrc,
    void* __restrict__ out, int n)
{
    const int wid  = threadIdx.x >> 6;
    const int lane = threadIdx.x & 63;
    const int ngroups = (n + 3) >> 2;

    for (int g = blockIdx.x; g < ngroups; g += gridDim.x) {
        const int node = g * 4 + wid;
        if (node >= n) continue;
        const int beg = offs[node];
        const int end = offs[node + 1];
        const float inv = 1.0f / fmaxf((float)(end - beg), 1.0f);

        if constexpr (DOUT == 128) {
            float ax[8], ay[8];
#pragma unroll
            for (int j = 0; j < 8; ++j) { ax[j] = 0.f; ay[j] = 0.f; }
            for (int e = beg; e < end; e += 8) {
#pragma unroll
                for (int j = 0; j < 8; ++j) {
                    const int idx = e + j;
                    const int ee  = min(idx, end - 1);
                    const float w = (idx < end) ? 1.0f : 0.0f;
                    const int s   = esrc[ee];
                    const unsigned int v = *(const unsigned int*)(&p[(size_t)s * DOUT + lane * 2]);
                    ax[j] = fmaf(w, bf16_hi_to_f32(v & 0xffffu), ax[j]);
                    ay[j] = fmaf(w, bf16_hi_to_f32(v >> 16), ay[j]);
                }
            }
            float sx = ((ax[0] + ax[1]) + (ax[2] + ax[3])) + ((ax[4] + ax[5]) + (ax[6] + ax[7]));
            float sy = ((ay[0] + ay[1]) + (ay[2] + ay[3])) + ((ay[4] + ay[5]) + (ay[6] + ay[7]));
            float rx, ry;
            if (R_BF16) {
                const unsigned int rv = ((const unsigned int*)r)[(size_t)node * (DOUT / 2) + lane];
                rx = bf16_hi_to_f32(rv & 0xffffu);
                ry = bf16_hi_to_f32(rv >> 16);
            } else {
                const float2 rv = *((const float2*)((const float*)r + (size_t)node * DOUT) + lane);
                rx = rv.x; ry = rv.y;
            }
            float ox = sx * inv + rx;
            float oy = sy * inv + ry;
            if (RELU) { ox = fmaxf(ox, 0.f); oy = fmaxf(oy, 0.f); }
            if (OUTBF16) {
                const unsigned int pk = ((unsigned int)f32_to_bf16(oy) << 16) | (unsigned int)f32_to_bf16(ox);
                ((unsigned int*)out)[(size_t)node * (DOUT / 2) + lane] = pk;
            } else {
                float2 o; o.x = ox; o.y = oy;
                *((float2*)((float*)out + (size_t)node * DOUT) + lane) = o;
            }
        } else {
            float a[8];
#pragma unroll
            for (int j = 0; j < 8; ++j) a[j] = 0.f;
            for (int e = beg; e < end; e += 8) {
#pragma unroll
                for (int j = 0; j < 8; ++j) {
                    const int idx = e + j;
                    const int ee  = min(idx, end - 1);
                    const float w = (idx < end) ? 1.0f : 0.0f;
                    const int s   = esrc[ee];
                    const unsigned short u = p[(size_t)s * DOUT + lane];
                    a[j] = fmaf(w, bf16_hi_to_f32((unsigned int)u), a[j]);
                }
            }
            float sa = ((a[0] + a[1]) + (a[2] + a[3])) + ((a[4] + a[5]) + (a[6] + a[7]));
            float rv;
            if (R_BF16) {
                const unsigned short u = ((const unsigned short*)r)[(size_t)node * DOUT + lane];
                rv = bf16_hi_to_f32((unsigned int)u);
            } else {
                rv = ((const float*)r)[(size_t)node * DOUT + lane];
            }
            float o = sa * inv + rv;
            if (RELU) o = fmaxf(o, 0.f);
            ((float*)out)[(size_t)node * DOUT + lane] = o;
        }
    }
}

// ---- the cooperative mega-kernel ------------------------------------------

__global__ __launch_bounds__(256, 4) void mega_kernel(MegaParams P)
{
    cg::grid_group grid = cg::this_grid();

    dev_init(P);
    __threadfence(); grid.sync();

    dev_hist(P);
    __threadfence(); grid.sync();

    dev_blocksum(P);
    __threadfence(); grid.sync();

    dev_scanwrite(P);
    __threadfence(); grid.sync();

    dev_fill(P);
    __threadfence(); grid.sync();

    dev_gemm<128, true, true>(P.x, P.wt0, P.b0, P.pbuf, P.rb16, P.N);
    __threadfence(); grid.sync();
    dev_agg<128, true, true, true>(P.pbuf, P.rb16, P.offs, P.esrc, P.hbf, P.N);
    __threadfence(); grid.sync();

    dev_gemm<128, false, true>(P.hbf, P.wt1, P.b1, P.pbuf, P.rb16, P.N);
    __threadfence(); grid.sync();
    dev_agg<128, true, true, true>(P.pbuf, P.rb16, P.offs, P.esrc, P.hbf, P.N);
    __threadfence(); grid.sync();

    dev_gemm<64, false, false>(P.hbf, P.wt2, P.b2, P.pbuf, P.rbf32, P.N);
    __threadfence(); grid.sync();
    dev_agg<64, false, false, false>(P.pbuf, P.rbf32, P.offs, P.esrc, P.out, P.N);
}

// ---- fallback wrappers (12-dispatch R13-equivalent path) ------------------

__global__ __launch_bounds__(256) void k_init(MegaParams P)      { dev_init(P); }
__global__ __launch_bounds__(256) void k_hist(MegaParams P)      { dev_hist(P); }
__global__ __launch_bounds__(256) void k_blocksum(MegaParams P)  { dev_blocksum(P); }
__global__ __launch_bounds__(256) void k_scanwrite(MegaParams P) { dev_scanwrite(P); }
__global__ __launch_bounds__(256) void k_fill(MegaParams P)      { dev_fill(P); }
__global__ __launch_bounds__(256) void k_gemm0(MegaParams P)
{ dev_gemm<128, true, true>(P.x, P.wt0, P.b0, P.pbuf, P.rb16, P.N); }
__global__ __launch_bounds__(256) void k_agg0(MegaParams P)
{ dev_agg<128, true, true, true>(P.pbuf, P.rb16, P.offs, P.esrc, P.hbf, P.N); }
__global__ __launch_bounds__(256) void k_gemm1(MegaParams P)
{ dev_gemm<128, false, true>(P.hbf, P.wt1, P.b1, P.pbuf, P.rb16, P.N); }
__global__ __launch_bounds__(256) void k_agg1(MegaParams P)
{ dev_agg<128, true, true, true>(P.pbuf, P.rb16, P.offs, P.esrc, P.hbf, P.N); }
__global__ __launch_bounds__(256) void k_gemm2(MegaParams P)
{ dev_gemm<64, false, false>(P.hbf, P.wt2, P.b2, P.pbuf, P.rbf32, P.N); }
__global__ __launch_bounds__(256) void k_agg2(MegaParams P)
{ dev_agg<64, false, false, false>(P.pbuf, P.rbf32, P.offs, P.esrc, P.out, P.N); }

// ---------------------------------------------------------------------------

static inline size_t align_up(size_t v, size_t a) { return (v + a - 1) & ~(a - 1); }

extern "C" void kernel_launch(void* const* d_in, const int* in_sizes, int n_in,
                              void* d_out, int out_size, void* d_ws, size_t ws_size,
                              hipStream_t stream)
{
    const int N = in_sizes[0] / HID;   // 50000
    const int E = in_sizes[1] / 2;     // 800000
    const int* ei = (const int*)d_in[1];   // int32! (harness converts int64)

    // Workspace carve-up (~42 MB)
    char*  ws  = (char*)d_ws;
    size_t off = 0;
    int* offs     = (int*)(ws + off); off = align_up(off + (size_t)(N + 1) * 4, 256);
    int* cursor   = (int*)(ws + off); off = align_up(off + (size_t)N * 4, 256);
    int* deg      = (int*)(ws + off); off = align_up(off + (size_t)N * 4, 256);
    int* partials = (int*)(ws + off); off = align_up(off + 256 * 4, 256);
    int* esrc     = (int*)(ws + off); off = align_up(off + (size_t)E * 4, 256);
    unsigned short* pbuf = (unsigned short*)(ws + off); off = align_up(off + (size_t)N * HID * 2, 256);
    unsigned short* rb16 = (unsigned short*)(ws + off); off = align_up(off + (size_t)N * HID * 2, 256);
    float* rbf32  = (float*)(ws + off); off = align_up(off + (size_t)N * HID * 4, 256);
    unsigned short* hbf = (unsigned short*)(ws + off); off = align_up(off + (size_t)N * HID * 2, 256);
    unsigned short* wt0 = (unsigned short*)(ws + off); off = align_up(off + (size_t)2 * HID * HID * 2, 256);
    unsigned short* wt1 = (unsigned short*)(ws + off); off = align_up(off + (size_t)2 * HID * HID * 2, 256);
    unsigned short* wt2 = (unsigned short*)(ws + off); off = align_up(off + (size_t)HID * HID * 2, 256);
    (void)ws_size; (void)n_in; (void)out_size;

    MegaParams P;
    P.x   = (const float*)d_in[0];
    P.src = ei;
    P.dst = ei + E;
    P.wl0 = (const float*)d_in[2];  P.b0 = (const float*)d_in[3];  P.wr0 = (const float*)d_in[4];
    P.wl1 = (const float*)d_in[5];  P.b1 = (const float*)d_in[6];  P.wr1 = (const float*)d_in[7];
    P.wl2 = (const float*)d_in[8];  P.b2 = (const float*)d_in[9];  P.wr2 = (const float*)d_in[10];
    P.out = (float*)d_out;
    P.N = N; P.E = E;
    P.offs = offs; P.cursor = cursor; P.deg = deg; P.partials = partials; P.esrc = esrc;
    P.pbuf = pbuf; P.rb16 = rb16; P.hbf = hbf;
    P.wt0 = wt0; P.wt1 = wt1; P.wt2 = wt2;
    P.rbf32 = rbf32;

    // --- size cooperative grid from queried occupancy (deterministic) ---
    int blocksPerCU = 0;
    hipError_t occErr = hipOccupancyMaxActiveBlocksPerMultiprocessor(
        &blocksPerCU, (const void*)mega_kernel, 256, 0);
    int grid = 0;
    if (occErr == hipSuccess && blocksPerCU > 0) {
        grid = blocksPerCU * 256;        // 256 CUs on MI355X
        if (grid > 1024) grid = 1024;
        grid &= ~7;                      // fill phase needs multiple of 8
    }

    bool launched = false;
    if (grid >= 8) {
        void* kargs[] = { (void*)&P };
        hipError_t e = hipLaunchCooperativeKernel(
            (const void*)mega_kernel, dim3(grid), dim3(256), kargs, 0, stream);
        launched = (e == hipSuccess);
    }

    if (!launched) {
        // --- proven 12-dispatch fallback (R13-equivalent) ---
        const int nScanBlk = (N + 1023) >> 10;            // 49
        const int aggGrid  = (N + 3) / 4;                 // 12500
        k_init<<<512, 256, 0, stream>>>(P);
        k_hist<<<(E + 255) / 256, 256, 0, stream>>>(P);
        k_blocksum<<<nScanBlk, 256, 0, stream>>>(P);
        k_scanwrite<<<nScanBlk, 256, 0, stream>>>(P);
        k_fill<<<832, 256, 0, stream>>>(P);
        k_gemm0<<<1024, 256, 0, stream>>>(P);
        k_agg0<<<aggGrid, 256, 0, stream>>>(P);
        k_gemm1<<<1024, 256, 0, stream>>>(P);
        k_agg1<<<aggGrid, 256, 0, stream>>>(P);
        k_gemm2<<<1024, 256, 0, stream>>>(P);
        k_agg2<<<aggGrid, 256, 0, stream>>>(P);
    }
}